// Round 7
// baseline (374.580 us; speedup 1.0000x reference)
//
#include <hip/hip_runtime.h>
#include <hip/hip_bf16.h>
#include <hip/hip_fp16.h>

#define SEQ    2048
#define DMODEL 2048
#define NH     16
#define NKV    4
#define HD     128
#define NTOT   3072   // DMODEL + 2*NKV*HD
#define MROWS  4096   // B*SEQ

typedef __attribute__((ext_vector_type(4))) float f32x4;
typedef __attribute__((ext_vector_type(8))) __bf16 bf16x8;
typedef __attribute__((ext_vector_type(8))) unsigned short u16x8;
typedef __attribute__((ext_vector_type(4))) unsigned short u16x4;

__device__ __forceinline__ void async_copy16(const void* g, void* l) {
  __builtin_amdgcn_global_load_lds(
      (const __attribute__((address_space(1))) void*)g,
      (__attribute__((address_space(3))) void*)l, 16, 0, 0);
}

__device__ __forceinline__ unsigned short fto16(float f) {
  __hip_bfloat16 h = __float2bfloat16(f);
  return *(unsigned short*)&h;
}

__device__ __forceinline__ float b2f(unsigned short u) {
  unsigned int t = (unsigned int)u << 16;
  float f;
  __builtin_memcpy(&f, &t, 4);
  return f;
}

// ---------------- fake-quant (all 4 weights in one launch) ----------------
__global__ __launch_bounds__(256) void fq_kernel(const float* __restrict__ Wq,
                                                 const float* __restrict__ Wk,
                                                 const float* __restrict__ Wv,
                                                 const float* __restrict__ Wp,
                                                 unsigned short* __restrict__ Wcat,
                                                 unsigned short* __restrict__ Wpq) {
  int g = blockIdx.x * 4 + (threadIdx.x >> 6);
  int lane = threadIdx.x & 63;
  const float* W;
  unsigned short* out;
  int blk;
  if (g < 32768)      { W = Wq; out = Wcat;                          blk = g; }
  else if (g < 40960) { W = Wk; out = Wcat + (size_t)2048 * 2048;    blk = g - 32768; }
  else if (g < 49152) { W = Wv; out = Wcat + (size_t)2560 * 2048;    blk = g - 40960; }
  else                { W = Wp; out = Wpq;                           blk = g - 49152; }
  const float* p = W + (size_t)blk * 128 + lane * 2;
  float w0 = p[0], w1 = p[1];
  float m = fmaxf(fabsf(w0), fabsf(w1));
#pragma unroll
  for (int o = 32; o; o >>= 1) m = fmaxf(m, __shfl_xor(m, o));
  float s = fmaxf(m / 31.0f, 1e-12f);
  s = __half2float(__float2half(s));        // fp16 RNE round of scale
  s = fmaxf(s, 6.103515625e-05f);           // fp16 tiny
  float q0 = rintf(fminf(fmaxf(w0 / s, -32.0f), 31.0f)) * s;
  float q1 = rintf(fminf(fmaxf(w1 / s, -32.0f), 31.0f)) * s;
  unsigned short* o16 = out + (size_t)blk * 128 + lane * 2;
  o16[0] = fto16(q0);
  o16[1] = fto16(q1);
}

// ---------------- fp32 -> bf16 convert ----------------
__global__ __launch_bounds__(256) void conv_kernel(const float* __restrict__ in,
                                                   unsigned short* __restrict__ out,
                                                   int n) {
  int i = (blockIdx.x * blockDim.x + threadIdx.x) * 4;
  if (i >= n) return;
  float4 v = *(const float4*)(in + i);
  ushort4 o;
  o.x = fto16(v.x); o.y = fto16(v.y); o.z = fto16(v.z); o.w = fto16(v.w);
  *(ushort4*)(out + i) = o;
}

// ---------------- bf16 MFMA GEMM, C[m,n] = sum_k A[m,k]*B[n,k] ----------------
// LDS swizzle via permuted global_load_lds SOURCE addresses (dest stays linear).
#define BM 128
#define BN 128
#define BK 32
template <typename OT>
__global__ __launch_bounds__(256) void gemm_bt(const unsigned short* __restrict__ A,
                                               const unsigned short* __restrict__ Bm,
                                               OT* __restrict__ C,
                                               int M, int N, int K) {
  __shared__ unsigned short As[BM * BK];
  __shared__ unsigned short Bs[BN * BK];
  const int tid = threadIdx.x;
  const int wave = tid >> 6, lane = tid & 63;
  const int quad = lane >> 4, l16 = lane & 15;
  const int m0 = blockIdx.x * BM, n0 = blockIdx.y * BN;
  const int wm = (wave >> 1) * 64, wn = (wave & 1) * 64;

  const unsigned short* Ag = A + (size_t)m0 * K;
  const unsigned short* Bg = Bm + (size_t)n0 * K;

  f32x4 acc[4][4];
#pragma unroll
  for (int i = 0; i < 4; i++)
#pragma unroll
    for (int j = 0; j < 4; j++) acc[i][j] = f32x4{0.f, 0.f, 0.f, 0.f};

  // swizzled staging source mapping (dest = linear lane*16B)
  const int rp  = lane >> 3;            // rowpair within 16-row segment
  const int ggs = (lane & 7) ^ rp;      // source combined granule
  const int sro = rp * 2 + (ggs >> 2);  // source row within segment
  const int sco = (ggs & 3) * 8;        // source col (elems)
  const int seg0 = wave * 2, seg1 = seg0 + 1;
  unsigned short* lA0 = &As[seg0 * 512];
  unsigned short* lA1 = &As[seg1 * 512];
  unsigned short* lB0 = &Bs[seg0 * 512];
  unsigned short* lB1 = &Bs[seg1 * 512];
  const unsigned short* gA0 = Ag + (size_t)(seg0 * 16 + sro) * K + sco;
  const unsigned short* gA1 = Ag + (size_t)(seg1 * 16 + sro) * K + sco;
  const unsigned short* gB0 = Bg + (size_t)(seg0 * 16 + sro) * K + sco;
  const unsigned short* gB1 = Bg + (size_t)(seg1 * 16 + sro) * K + sco;

  // frag read offset (row = wm/wn + t*16 + l16, g = quad)
  const int fbase = (l16 >> 1) * 64 + ((((((l16 & 1) << 2) | quad)) ^ ((l16 >> 1) & 7)) << 3);

  for (int k0 = 0; k0 < K; k0 += BK) {
    __syncthreads();
    async_copy16(gA0 + k0, lA0);
    async_copy16(gA1 + k0, lA1);
    async_copy16(gB0 + k0, lB0);
    async_copy16(gB1 + k0, lB1);
    __syncthreads();
    bf16x8 af[4], bf[4];
#pragma unroll
    for (int t = 0; t < 4; t++)
      af[t] = *(const bf16x8*)&As[(wm + t * 16) * 32 + fbase];
#pragma unroll
    for (int t = 0; t < 4; t++)
      bf[t] = *(const bf16x8*)&Bs[(wn + t * 16) * 32 + fbase];
#pragma unroll
    for (int i = 0; i < 4; i++)
#pragma unroll
      for (int j = 0; j < 4; j++)
        acc[i][j] = __builtin_amdgcn_mfma_f32_16x16x32_bf16(af[i], bf[j], acc[i][j], 0, 0, 0);
  }
#pragma unroll
  for (int i = 0; i < 4; i++) {
    int row_base = m0 + wm + i * 16 + quad * 4;
#pragma unroll
    for (int j = 0; j < 4; j++) {
      int col = n0 + wn + j * 16 + l16;
#pragma unroll
      for (int r = 0; r < 4; r++) {
        if constexpr (sizeof(OT) == 2)
          C[(size_t)(row_base + r) * N + col] = fto16(acc[i][j][r]);
        else
          C[(size_t)(row_base + r) * N + col] = acc[i][j][r];
      }
    }
  }
}

// ---------------- RMSNorm + RoPE + gain (Q,K only), bf16 in/out ----------------
#define QSCALE 0.12751791437524245f   // (1/sqrt(128)) * log2(e)
__global__ __launch_bounds__(256) void normrope_kernel(const unsigned short* __restrict__ qkvb,
                                                       const float* __restrict__ qgain,
                                                       unsigned short* __restrict__ qbuf,
                                                       unsigned short* __restrict__ kbuf) {
  const int i = blockIdx.x;            // token 0..4095
  const int bz = i >> 11, tok = i & 2047;
  const int wave = threadIdx.x >> 6, lane = threadIdx.x & 63;
  const unsigned short* row = qkvb + (size_t)i * NTOT;

  // 10000^(-2*lane/128) = 2^(-2*lane*log2(1e4)/128)
  float invf = exp2f(-0.10381025296f * (float)(2 * lane));
  float freq = (float)tok * invf;
  float cs, sn;
  __sincosf(freq, &sn, &cs);

  for (int slot = wave; slot < 20; slot += 4) {
    if (slot < 16) {                   // q heads: norm + rope + gain*scale
      int hh = slot;
      const unsigned short* src = row + hh * HD;
      float x1 = b2f(src[lane]), x2 = b2f(src[lane + 64]);
      float ss = x1 * x1 + x2 * x2;
#pragma unroll
      for (int o = 32; o; o >>= 1) ss += __shfl_xor(ss, o);
      float rn = rsqrtf(ss * (1.0f / 128.0f) + 1.1920929e-07f);
      float n1 = x1 * rn, n2 = x2 * rn;
      float g = qgain[hh] * QSCALE;
      unsigned short* dst = qbuf + ((size_t)(bz * NH + hh) * SEQ + tok) * HD;
      dst[lane]      = fto16((n1 * cs + n2 * sn) * g);
      dst[lane + 64] = fto16((-n1 * sn + n2 * cs) * g);
    } else {                           // k heads: norm + rope
      int hh = slot - 16;
      const unsigned short* src = row + DMODEL + hh * HD;
      float x1 = b2f(src[lane]), x2 = b2f(src[lane + 64]);
      float ss = x1 * x1 + x2 * x2;
#pragma unroll
      for (int o = 32; o; o >>= 1) ss += __shfl_xor(ss, o);
      float rn = rsqrtf(ss * (1.0f / 128.0f) + 1.1920929e-07f);
      float n1 = x1 * rn, n2 = x2 * rn;
      unsigned short* dst = kbuf + ((size_t)(bz * NKV + hh) * SEQ + tok) * HD;
      dst[lane]      = fto16(n1 * cs + n2 * sn);
      dst[lane + 64] = fto16(-n1 * sn + n2 * cs);
    }
  }
}

// ---------------- V transpose: bf16 qkv v-section -> bf16 V^T [b,kvh,d,s] ----------------
__global__ __launch_bounds__(256) void vtrans_kernel(const unsigned short* __restrict__ qkvb,
                                                     unsigned short* __restrict__ vtb) {
  __shared__ unsigned short T[64 * 72];
  const int s0 = blockIdx.x * 64;
  const int d0 = blockIdx.y * 64;
  const int bz = blockIdx.z >> 2, h = blockIdx.z & 3;
  const int tid = threadIdx.x;
#pragma unroll
  for (int i = 0; i < 2; ++i) {
    int c = i * 256 + tid;
    int s = c >> 3, ch = c & 7;
    const unsigned short* src =
        qkvb + (size_t)(bz * SEQ + s0 + s) * NTOT + DMODEL + 512 + h * HD + d0 + ch * 8;
    *(u16x8*)&T[s * 72 + ch * 8] = *(const u16x8*)src;
  }
  __syncthreads();
  unsigned short* outg = vtb + (size_t)(bz * NKV + h) * HD * SEQ;
#pragma unroll
  for (int i = 0; i < 2; ++i) {
    int c = i * 256 + tid;
    int d = c >> 3, sc = c & 7;
    u16x8 v;
#pragma unroll
    for (int j = 0; j < 8; ++j) v[j] = T[(sc * 8 + j) * 72 + d];
    *(u16x8*)(outg + (size_t)(d0 + d) * SEQ + s0 + sc * 8) = v;
  }
}

// ---------------- flash attention: 64-row Q tile, 1024 blocks, O^T form ----------
// Each wave owns 16 q-rows; 64-row tiles align with 64-kp tiles so causal
// skip/mask decisions are wave-uniform. LDS 40KB -> 4 blocks/CU.
__global__ __launch_bounds__(256, 4) void attn_kernel(const unsigned short* __restrict__ qb,
                                                      const unsigned short* __restrict__ kb,
                                                      const unsigned short* __restrict__ vtb,
                                                      unsigned short* __restrict__ yb) {
  __shared__ unsigned short Ks[64 * 128];     // [kpos][d] swizzled, 16 KB
  __shared__ unsigned short Vt[128 * 64];     // [d][kpos] swizzled, 16 KB
  __shared__ unsigned short Ps[4][16 * 64];   // per-wave P [q16][kpos64], 8 KB

  const int bx = blockIdx.x;
  const int h = blockIdx.y;
  const int bz = blockIdx.z;
  // interleaved pairing: any 4 consecutive bx sum to 66 k-tile units
  const int qt = (bx & 1) ? (bx >> 1) : (31 - (bx >> 1));
  const int tid = threadIdx.x;
  const int wave = tid >> 6, lane = tid & 63;
  const int quad = lane >> 4, l16 = lane & 15;
  const int q0 = qt * 64;
  const int qrow = q0 + wave * 16 + l16;     // this lane's softmax row

  const unsigned short* qg = qb + (size_t)(bz * NH + h) * SEQ * HD;
  const unsigned short* kg = kb + (size_t)(bz * NKV + (h >> 2)) * SEQ * HD;
  const unsigned short* vg = vtb + (size_t)(bz * NKV + (h >> 2)) * HD * SEQ;
  unsigned short* psw = &Ps[wave][0];

  bf16x8 qf[4];
#pragma unroll
  for (int ds = 0; ds < 4; ++ds)
    qf[ds] = *(const bf16x8*)(qg + (size_t)qrow * HD + ds * 32 + quad * 8);

  f32x4 oacc[8];                        // O^T C-layout: row=d, col=q(=l16)
#pragma unroll
  for (int j = 0; j < 8; ++j) oacc[j] = f32x4{0.f, 0.f, 0.f, 0.f};
  float m_i = -__builtin_inff(), l_i = 0.f;

  // staging thread mapping
  const int krw = tid >> 4, kgr = tid & 15;   // K: 16 rows/iter
  const int vdw = tid >> 3, vgr = tid & 7;    // V: 32 d/iter
  const int nkt = qt + 1;

  u16x8 pk[4], pv[4];
#pragma unroll
  for (int i = 0; i < 4; ++i)
    pk[i] = *(const u16x8*)(kg + (size_t)(i * 16 + krw) * HD + kgr * 8);
#pragma unroll
  for (int i = 0; i < 4; ++i)
    pv[i] = *(const u16x8*)(vg + (size_t)(i * 32 + vdw) * SEQ + vgr * 8);

  for (int kt = 0; kt < nkt; ++kt) {
#pragma unroll
    for (int i = 0; i < 4; ++i) {
      int row = i * 16 + krw;
      *(u16x8*)&Ks[row * 128 + ((kgr ^ (row & 15)) << 3)] = pk[i];
    }
#pragma unroll
    for (int i = 0; i < 4; ++i) {
      int d = i * 32 + vdw;
      *(u16x8*)&Vt[d * 64 + ((vgr ^ (d & 7)) << 3)] = pv[i];
    }
    __syncthreads();

    if (kt + 1 < nkt) {                // register prefetch of next tile
#pragma unroll
      for (int i = 0; i < 4; ++i)
        pk[i] = *(const u16x8*)(kg + (size_t)((kt + 1) * 64 + i * 16 + krw) * HD + kgr * 8);
#pragma unroll
      for (int i = 0; i < 4; ++i)
        pv[i] = *(const u16x8*)(vg + (size_t)(i * 32 + vdw) * SEQ + (kt + 1) * 64 + vgr * 8);
    }

    // ---- S^T = K * Q^T ----
    f32x4 st[4];
#pragma unroll
    for (int mt = 0; mt < 4; ++mt) {
      st[mt] = f32x4{0.f, 0.f, 0.f, 0.f};
#pragma unroll
      for (int ds = 0; ds < 4; ++ds) {
        bf16x8 kf = *(const bf16x8*)&Ks[(mt * 16 + l16) * 128 + ((((ds << 2) + quad) ^ l16) << 3)];
        st[mt] = __builtin_amdgcn_mfma_f32_16x16x32_bf16(kf, qf[ds], st[mt], 0, 0, 0);
      }
    }

    // ---- online softmax (exp2 domain; state keyed by l16) ----
    float p[4][4];
    float mx = -__builtin_inff();
    if (kt == qt) {                    // diagonal tile: causal mask
#pragma unroll
      for (int mt = 0; mt < 4; ++mt)
#pragma unroll
        for (int r = 0; r < 4; ++r) {
          int kp = kt * 64 + mt * 16 + quad * 4 + r;
          float v = (kp <= qrow) ? st[mt][r] : -__builtin_inff();
          p[mt][r] = v;
          mx = fmaxf(mx, v);
        }
    } else {
#pragma unroll
      for (int mt = 0; mt < 4; ++mt)
#pragma unroll
        for (int r = 0; r < 4; ++r) {
          p[mt][r] = st[mt][r];
          mx = fmaxf(mx, st[mt][r]);
        }
    }
    mx = fmaxf(mx, __shfl_xor(mx, 16));
    mx = fmaxf(mx, __shfl_xor(mx, 32));
    float mnew = fmaxf(m_i, mx);
    float rs = 0.f;
#pragma unroll
    for (int mt = 0; mt < 4; ++mt)
#pragma unroll
      for (int r = 0; r < 4; ++r) {
        float e = exp2f(p[mt][r] - mnew);
        p[mt][r] = e;
        rs += e;
      }
    rs += __shfl_xor(rs, 16);
    rs += __shfl_xor(rs, 32);
    if (__any(mnew > m_i)) {           // rescale only when max moved
      float a = exp2f(m_i - mnew);
#pragma unroll
      for (int j = 0; j < 8; ++j) oacc[j] *= a;
      l_i = l_i * a + rs;
    } else {
      l_i += rs;
    }
    m_i = mnew;

    // ---- P store (swizzled, per-wave buffer) ----
#pragma unroll
    for (int mt = 0; mt < 4; ++mt) {
      u16x4 w;
#pragma unroll
      for (int r = 0; r < 4; ++r) w[r] = fto16(p[mt][r]);
      int g = mt * 2 + (quad >> 1);
      *(u16x4*)&psw[l16 * 64 + ((g ^ (l16 & 7)) << 3) + (quad & 1) * 4] = w;
    }

    __asm__ volatile("s_waitcnt lgkmcnt(0)" ::: "memory");  // own P writes -> reads

    // ---- O^T += V^T * P^T ----
#pragma unroll
    for (int c = 0; c < 2; ++c) {
      bf16x8 pf = *(const bf16x8*)&psw[l16 * 64 + ((((c << 2) + quad) ^ (l16 & 7)) << 3)];
#pragma unroll
      for (int dt = 0; dt < 8; ++dt) {
        bf16x8 vf = *(const bf16x8*)&Vt[(dt * 16 + l16) * 64 + ((((c << 2) + quad) ^ (l16 & 7)) << 3)];
        oacc[dt] = __builtin_amdgcn_mfma_f32_16x16x32_bf16(vf, pf, oacc[dt], 0, 0, 0);
      }
    }
    __syncthreads();                   // all LDS reads done before next stores
  }

  // epilogue: O^T row = d = dt*16+quad*4+r, col = q = l16; per-lane invl
  float il = 1.0f / l_i;
#pragma unroll
  for (int dt = 0; dt < 8; ++dt) {
    u16x4 o;
#pragma unroll
    for (int r = 0; r < 4; ++r) o[r] = fto16(oacc[dt][r] * il);
    *(u16x4*)&yb[(size_t)(bz * SEQ + qrow) * DMODEL + h * HD + dt * 16 + quad * 4] = o;
  }
}

extern "C" void kernel_launch(void* const* d_in, const int* in_sizes, int n_in,
                              void* d_out, int out_size, void* d_ws, size_t ws_size,
                              hipStream_t stream) {
  (void)in_sizes; (void)n_in; (void)out_size; (void)ws_size;
  const float* x  = (const float*)d_in[0];
  const float* Wq = (const float*)d_in[1];
  const float* Wk = (const float*)d_in[2];
  const float* Wv = (const float*)d_in[3];
  const float* Wp = (const float*)d_in[4];
  const float* qg = (const float*)d_in[5];
  float* out = (float*)d_out;
  char* ws = (char*)d_ws;

  // workspace layout; yb aliases xb (x consumed by GEMM1 before attn writes y)
  unsigned short* xb   = (unsigned short*)(ws + 0);          // 16.78 MB
  unsigned short* Wcat = (unsigned short*)(ws + 16777216);   // 12.58 MB (Wq|Wk|Wv rows)
  unsigned short* Wpq  = (unsigned short*)(ws + 29360128);   // 8.39 MB
  unsigned short* qkvb = (unsigned short*)(ws + 37748736);   // 25.17 MB (bf16 qkv)
  unsigned short* qbuf = (unsigned short*)(ws + 62914560);   // 16.78 MB
  unsigned short* kbuf = (unsigned short*)(ws + 79691776);   // 4.19 MB
  unsigned short* vtb  = (unsigned short*)(ws + 83886080);   // 4.19 MB (V^T)
  unsigned short* yb   = xb;

  fq_kernel<<<81920 / 4, 256, 0, stream>>>(Wq, Wk, Wv, Wp, Wcat, Wpq);
  conv_kernel<<<8388608 / 1024, 256, 0, stream>>>(x, xb, 8388608);
  gemm_bt<unsigned short><<<dim3(32, 24), 256, 0, stream>>>(xb, Wcat, qkvb, MROWS, NTOT, DMODEL);
  normrope_kernel<<<MROWS, 256, 0, stream>>>(qkvb, qg, qbuf, kbuf);
  vtrans_kernel<<<dim3(32, 2, 8), 256, 0, stream>>>(qkvb, vtb);
  attn_kernel<<<dim3(32, NH, 2), 256, 0, stream>>>(qbuf, kbuf, vtb, yb);
  gemm_bt<float><<<dim3(32, 16), 256, 0, stream>>>(yb, Wpq, out, MROWS, DMODEL, DMODEL);
}

// Round 8
// 354.753 us; speedup vs baseline: 1.0559x; 1.0559x over previous
//
#include <hip/hip_runtime.h>
#include <hip/hip_bf16.h>
#include <hip/hip_fp16.h>

#define SEQ    2048
#define DMODEL 2048
#define NH     16
#define NKV    4
#define HD     128
#define NTOT   3072   // DMODEL + 2*NKV*HD
#define MROWS  4096   // B*SEQ

typedef __attribute__((ext_vector_type(4))) float f32x4;
typedef __attribute__((ext_vector_type(8))) __bf16 bf16x8;
typedef __attribute__((ext_vector_type(8))) unsigned short u16x8;
typedef __attribute__((ext_vector_type(4))) unsigned short u16x4;

__device__ __forceinline__ void async_copy16(const void* g, void* l) {
  __builtin_amdgcn_global_load_lds(
      (const __attribute__((address_space(1))) void*)g,
      (__attribute__((address_space(3))) void*)l, 16, 0, 0);
}

__device__ __forceinline__ unsigned short fto16(float f) {
  __hip_bfloat16 h = __float2bfloat16(f);
  return *(unsigned short*)&h;
}

__device__ __forceinline__ float b2f(unsigned short u) {
  unsigned int t = (unsigned int)u << 16;
  float f;
  __builtin_memcpy(&f, &t, 4);
  return f;
}

// ---------------- prep: fake-quant all 4 weights + x fp32->bf16, one launch ----------------
__global__ __launch_bounds__(256) void prep_kernel(const float* __restrict__ Wq,
                                                   const float* __restrict__ Wk,
                                                   const float* __restrict__ Wv,
                                                   const float* __restrict__ Wp,
                                                   const float* __restrict__ x,
                                                   unsigned short* __restrict__ Wcat,
                                                   unsigned short* __restrict__ Wpq,
                                                   unsigned short* __restrict__ xb) {
  const int b = blockIdx.x;
  if (b < 20480) {                       // fake-quant: one wave per 128-block
    int g = b * 4 + (threadIdx.x >> 6);
    int lane = threadIdx.x & 63;
    const float* W;
    unsigned short* out;
    int blk;
    if (g < 32768)      { W = Wq; out = Wcat;                       blk = g; }
    else if (g < 40960) { W = Wk; out = Wcat + (size_t)2048 * 2048; blk = g - 32768; }
    else if (g < 49152) { W = Wv; out = Wcat + (size_t)2560 * 2048; blk = g - 40960; }
    else                { W = Wp; out = Wpq;                        blk = g - 49152; }
    const float* p = W + (size_t)blk * 128 + lane * 2;
    float w0 = p[0], w1 = p[1];
    float m = fmaxf(fabsf(w0), fabsf(w1));
#pragma unroll
    for (int o = 32; o; o >>= 1) m = fmaxf(m, __shfl_xor(m, o));
    float s = fmaxf(m / 31.0f, 1e-12f);
    s = __half2float(__float2half(s));      // fp16 RNE round of scale
    s = fmaxf(s, 6.103515625e-05f);         // fp16 tiny
    float q0 = rintf(fminf(fmaxf(w0 / s, -32.0f), 31.0f)) * s;
    float q1 = rintf(fminf(fmaxf(w1 / s, -32.0f), 31.0f)) * s;
    unsigned short* o16 = out + (size_t)blk * 128 + lane * 2;
    o16[0] = fto16(q0);
    o16[1] = fto16(q1);
  } else {                                // x convert: 1024 elems per block
    int i = (b - 20480) * 1024 + threadIdx.x * 4;
    float4 v = *(const float4*)(x + i);
    ushort4 o;
    o.x = fto16(v.x); o.y = fto16(v.y); o.z = fto16(v.z); o.w = fto16(v.w);
    *(ushort4*)(xb + i) = o;
  }
}

// ---------------- bf16 MFMA GEMM, C[m,n] = sum_k A[m,k]*B[n,k] ----------------
// LDS swizzle via permuted global_load_lds SOURCE addresses (dest stays linear).
#define BM 128
#define BN 128
#define BK 32
template <typename OT>
__global__ __launch_bounds__(256) void gemm_bt(const unsigned short* __restrict__ A,
                                               const unsigned short* __restrict__ Bm,
                                               OT* __restrict__ C,
                                               int M, int N, int K) {
  __shared__ unsigned short As[BM * BK];
  __shared__ unsigned short Bs[BN * BK];
  const int tid = threadIdx.x;
  const int wave = tid >> 6, lane = tid & 63;
  const int quad = lane >> 4, l16 = lane & 15;
  const int m0 = blockIdx.x * BM, n0 = blockIdx.y * BN;
  const int wm = (wave >> 1) * 64, wn = (wave & 1) * 64;

  const unsigned short* Ag = A + (size_t)m0 * K;
  const unsigned short* Bg = Bm + (size_t)n0 * K;

  f32x4 acc[4][4];
#pragma unroll
  for (int i = 0; i < 4; i++)
#pragma unroll
    for (int j = 0; j < 4; j++) acc[i][j] = f32x4{0.f, 0.f, 0.f, 0.f};

  // swizzled staging source mapping (dest = linear lane*16B)
  const int rp  = lane >> 3;
  const int ggs = (lane & 7) ^ rp;
  const int sro = rp * 2 + (ggs >> 2);
  const int sco = (ggs & 3) * 8;
  const int seg0 = wave * 2, seg1 = seg0 + 1;
  unsigned short* lA0 = &As[seg0 * 512];
  unsigned short* lA1 = &As[seg1 * 512];
  unsigned short* lB0 = &Bs[seg0 * 512];
  unsigned short* lB1 = &Bs[seg1 * 512];
  const unsigned short* gA0 = Ag + (size_t)(seg0 * 16 + sro) * K + sco;
  const unsigned short* gA1 = Ag + (size_t)(seg1 * 16 + sro) * K + sco;
  const unsigned short* gB0 = Bg + (size_t)(seg0 * 16 + sro) * K + sco;
  const unsigned short* gB1 = Bg + (size_t)(seg1 * 16 + sro) * K + sco;

  const int fbase = (l16 >> 1) * 64 + ((((((l16 & 1) << 2) | quad)) ^ ((l16 >> 1) & 7)) << 3);

  for (int k0 = 0; k0 < K; k0 += BK) {
    __syncthreads();
    async_copy16(gA0 + k0, lA0);
    async_copy16(gA1 + k0, lA1);
    async_copy16(gB0 + k0, lB0);
    async_copy16(gB1 + k0, lB1);
    __syncthreads();
    bf16x8 af[4], bf[4];
#pragma unroll
    for (int t = 0; t < 4; t++)
      af[t] = *(const bf16x8*)&As[(wm + t * 16) * 32 + fbase];
#pragma unroll
    for (int t = 0; t < 4; t++)
      bf[t] = *(const bf16x8*)&Bs[(wn + t * 16) * 32 + fbase];
#pragma unroll
    for (int i = 0; i < 4; i++)
#pragma unroll
      for (int j = 0; j < 4; j++)
        acc[i][j] = __builtin_amdgcn_mfma_f32_16x16x32_bf16(af[i], bf[j], acc[i][j], 0, 0, 0);
  }
#pragma unroll
  for (int i = 0; i < 4; i++) {
    int row_base = m0 + wm + i * 16 + quad * 4;
#pragma unroll
    for (int j = 0; j < 4; j++) {
      int col = n0 + wn + j * 16 + l16;
#pragma unroll
      for (int r = 0; r < 4; r++) {
        if constexpr (sizeof(OT) == 2)
          C[(size_t)(row_base + r) * N + col] = fto16(acc[i][j][r]);
        else
          C[(size_t)(row_base + r) * N + col] = acc[i][j][r];
      }
    }
  }
}

// ---------------- RMSNorm+RoPE+gain AND V-transpose, one launch ----------------
#define QSCALE 0.12751791437524245f   // (1/sqrt(128)) * log2(e)
__global__ __launch_bounds__(256) void postq_kernel(const unsigned short* __restrict__ qkvb,
                                                    const float* __restrict__ qgain,
                                                    unsigned short* __restrict__ qbuf,
                                                    unsigned short* __restrict__ kbuf,
                                                    unsigned short* __restrict__ vtb) {
  const int b = blockIdx.x;
  if (b < MROWS) {                       // ---- normrope: one token per block ----
    const int bz = b >> 11, tok = b & 2047;
    const int wave = threadIdx.x >> 6, lane = threadIdx.x & 63;
    const unsigned short* row = qkvb + (size_t)b * NTOT;

    float invf = exp2f(-0.10381025296f * (float)(2 * lane));
    float freq = (float)tok * invf;
    float cs, sn;
    __sincosf(freq, &sn, &cs);

    for (int slot = wave; slot < 20; slot += 4) {
      if (slot < 16) {
        int hh = slot;
        const unsigned short* src = row + hh * HD;
        float x1 = b2f(src[lane]), x2 = b2f(src[lane + 64]);
        float ss = x1 * x1 + x2 * x2;
#pragma unroll
        for (int o = 32; o; o >>= 1) ss += __shfl_xor(ss, o);
        float rn = rsqrtf(ss * (1.0f / 128.0f) + 1.1920929e-07f);
        float n1 = x1 * rn, n2 = x2 * rn;
        float g = qgain[hh] * QSCALE;
        unsigned short* dst = qbuf + ((size_t)(bz * NH + hh) * SEQ + tok) * HD;
        dst[lane]      = fto16((n1 * cs + n2 * sn) * g);
        dst[lane + 64] = fto16((-n1 * sn + n2 * cs) * g);
      } else {
        int hh = slot - 16;
        const unsigned short* src = row + DMODEL + hh * HD;
        float x1 = b2f(src[lane]), x2 = b2f(src[lane + 64]);
        float ss = x1 * x1 + x2 * x2;
#pragma unroll
        for (int o = 32; o; o >>= 1) ss += __shfl_xor(ss, o);
        float rn = rsqrtf(ss * (1.0f / 128.0f) + 1.1920929e-07f);
        float n1 = x1 * rn, n2 = x2 * rn;
        unsigned short* dst = kbuf + ((size_t)(bz * NKV + hh) * SEQ + tok) * HD;
        dst[lane]      = fto16(n1 * cs + n2 * sn);
        dst[lane + 64] = fto16(-n1 * sn + n2 * cs);
      }
    }
  } else {                               // ---- vtrans: 64x64 tile per block ----
    __shared__ unsigned short T[64 * 72];
    const int v = b - MROWS;             // 0..511
    const int s0 = (v & 31) * 64;
    const int d0 = ((v >> 5) & 1) * 64;
    const int bz = v >> 8, h = (v >> 6) & 3;
    const int tid = threadIdx.x;
#pragma unroll
    for (int i = 0; i < 2; ++i) {
      int c = i * 256 + tid;
      int s = c >> 3, ch = c & 7;
      const unsigned short* src =
          qkvb + (size_t)(bz * SEQ + s0 + s) * NTOT + DMODEL + 512 + h * HD + d0 + ch * 8;
      *(u16x8*)&T[s * 72 + ch * 8] = *(const u16x8*)src;
    }
    __syncthreads();
    unsigned short* outg = vtb + (size_t)(bz * NKV + h) * HD * SEQ;
#pragma unroll
    for (int i = 0; i < 2; ++i) {
      int c = i * 256 + tid;
      int d = c >> 3, sc = c & 7;
      u16x8 vv;
#pragma unroll
      for (int j = 0; j < 8; ++j) vv[j] = T[(sc * 8 + j) * 72 + d];
      *(u16x8*)(outg + (size_t)(d0 + d) * SEQ + s0 + sc * 8) = vv;
    }
  }
}

// ---------------- flash attention: sequential complement pairs, 64-row tiles ----
// Every block = exactly 33 k-tile units (qt in {pair, 31-pair} done sequentially)
// -> uniform block duration, co-resident blocks stay in lockstep (no tail).
__global__ __launch_bounds__(256, 4) void attn_kernel(const unsigned short* __restrict__ qb,
                                                      const unsigned short* __restrict__ kb,
                                                      const unsigned short* __restrict__ vtb,
                                                      unsigned short* __restrict__ yb) {
  __shared__ unsigned short Ks[64 * 128];     // [kpos][d] swizzled, 16 KB
  __shared__ unsigned short Vt[128 * 64];     // [d][kpos] swizzled, 16 KB
  __shared__ unsigned short Ps[4][16 * 64];   // per-wave P [q16][kpos64], 8 KB

  const int pair = blockIdx.x;
  const int h = blockIdx.y;
  const int bz = blockIdx.z;
  const int tid = threadIdx.x;
  const int wave = tid >> 6, lane = tid & 63;
  const int quad = lane >> 4, l16 = lane & 15;

  const unsigned short* qg = qb + (size_t)(bz * NH + h) * SEQ * HD;
  const unsigned short* kg = kb + (size_t)(bz * NKV + (h >> 2)) * SEQ * HD;
  const unsigned short* vg = vtb + (size_t)(bz * NKV + (h >> 2)) * HD * SEQ;
  unsigned short* psw = &Ps[wave][0];

  // staging thread mapping
  const int krw = tid >> 4, kgr = tid & 15;   // K: 16 rows/iter
  const int vdw = tid >> 3, vgr = tid & 7;    // V: 32 d/iter

  const int qts[2] = {pair, 31 - pair};

  // initial global prefetch (kt = 0; also correct for tile-boundary restart)
  u16x8 pk[4], pv[4];
#pragma unroll
  for (int i = 0; i < 4; ++i)
    pk[i] = *(const u16x8*)(kg + (size_t)(i * 16 + krw) * HD + kgr * 8);
#pragma unroll
  for (int i = 0; i < 4; ++i)
    pv[i] = *(const u16x8*)(vg + (size_t)(i * 32 + vdw) * SEQ + vgr * 8);

  for (int ti = 0; ti < 2; ++ti) {
    const int qt = qts[ti];
    const int q0 = qt * 64;
    const int qrow = q0 + wave * 16 + l16;
    const int nkt = qt + 1;

    bf16x8 qf[4];
#pragma unroll
    for (int ds = 0; ds < 4; ++ds)
      qf[ds] = *(const bf16x8*)(qg + (size_t)qrow * HD + ds * 32 + quad * 8);

    f32x4 oacc[8];
#pragma unroll
    for (int j = 0; j < 8; ++j) oacc[j] = f32x4{0.f, 0.f, 0.f, 0.f};
    float m_i = -__builtin_inff(), l_i = 0.f;

    for (int kt = 0; kt < nkt; ++kt) {
#pragma unroll
      for (int i = 0; i < 4; ++i) {
        int row = i * 16 + krw;
        *(u16x8*)&Ks[row * 128 + ((kgr ^ (row & 15)) << 3)] = pk[i];
      }
#pragma unroll
      for (int i = 0; i < 4; ++i) {
        int d = i * 32 + vdw;
        *(u16x8*)&Vt[d * 64 + ((vgr ^ (d & 7)) << 3)] = pv[i];
      }
      __syncthreads();

      // prefetch next staging tile: kt+1 within tile, or kt=0 for next q-tile
      {
        int nk = (kt + 1 < nkt) ? (kt + 1) : 0;
        bool want = (kt + 1 < nkt) || (ti == 0);
        if (want) {
#pragma unroll
          for (int i = 0; i < 4; ++i)
            pk[i] = *(const u16x8*)(kg + (size_t)(nk * 64 + i * 16 + krw) * HD + kgr * 8);
#pragma unroll
          for (int i = 0; i < 4; ++i)
            pv[i] = *(const u16x8*)(vg + (size_t)(i * 32 + vdw) * SEQ + nk * 64 + vgr * 8);
        }
      }

      // ---- S^T = K * Q^T ----
      f32x4 st[4];
#pragma unroll
      for (int mt = 0; mt < 4; ++mt) {
        st[mt] = f32x4{0.f, 0.f, 0.f, 0.f};
#pragma unroll
        for (int ds = 0; ds < 4; ++ds) {
          bf16x8 kf = *(const bf16x8*)&Ks[(mt * 16 + l16) * 128 + ((((ds << 2) + quad) ^ l16) << 3)];
          st[mt] = __builtin_amdgcn_mfma_f32_16x16x32_bf16(kf, qf[ds], st[mt], 0, 0, 0);
        }
      }

      // ---- online softmax (exp2 domain; state keyed by l16) ----
      float p[4][4];
      float mx = -__builtin_inff();
      if (kt == qt) {                    // diagonal tile: causal mask
#pragma unroll
        for (int mt = 0; mt < 4; ++mt)
#pragma unroll
          for (int r = 0; r < 4; ++r) {
            int kp = kt * 64 + mt * 16 + quad * 4 + r;
            float v = (kp <= qrow) ? st[mt][r] : -__builtin_inff();
            p[mt][r] = v;
            mx = fmaxf(mx, v);
          }
      } else {
#pragma unroll
        for (int mt = 0; mt < 4; ++mt)
#pragma unroll
          for (int r = 0; r < 4; ++r) {
            p[mt][r] = st[mt][r];
            mx = fmaxf(mx, st[mt][r]);
          }
      }
      mx = fmaxf(mx, __shfl_xor(mx, 16));
      mx = fmaxf(mx, __shfl_xor(mx, 32));
      float mnew = fmaxf(m_i, mx);
      float rs = 0.f;
#pragma unroll
      for (int mt = 0; mt < 4; ++mt)
#pragma unroll
        for (int r = 0; r < 4; ++r) {
          float e = exp2f(p[mt][r] - mnew);
          p[mt][r] = e;
          rs += e;
        }
      rs += __shfl_xor(rs, 16);
      rs += __shfl_xor(rs, 32);
      if (__any(mnew > m_i)) {
        float a = exp2f(m_i - mnew);
#pragma unroll
        for (int j = 0; j < 8; ++j) oacc[j] *= a;
        l_i = l_i * a + rs;
      } else {
        l_i += rs;
      }
      m_i = mnew;

      // ---- P store (swizzled, per-wave buffer) ----
#pragma unroll
      for (int mt = 0; mt < 4; ++mt) {
        u16x4 w;
#pragma unroll
        for (int r = 0; r < 4; ++r) w[r] = fto16(p[mt][r]);
        int g = mt * 2 + (quad >> 1);
        *(u16x4*)&psw[l16 * 64 + ((g ^ (l16 & 7)) << 3) + (quad & 1) * 4] = w;
      }

      __asm__ volatile("s_waitcnt lgkmcnt(0)" ::: "memory");

      // ---- O^T += V^T * P^T ----
#pragma unroll
      for (int c = 0; c < 2; ++c) {
        bf16x8 pf = *(const bf16x8*)&psw[l16 * 64 + ((((c << 2) + quad) ^ (l16 & 7)) << 3)];
#pragma unroll
        for (int dt = 0; dt < 8; ++dt) {
          bf16x8 vf = *(const bf16x8*)&Vt[(dt * 16 + l16) * 64 + ((((c << 2) + quad) ^ (l16 & 7)) << 3)];
          oacc[dt] = __builtin_amdgcn_mfma_f32_16x16x32_bf16(vf, pf, oacc[dt], 0, 0, 0);
        }
      }
      __syncthreads();
    }

    // epilogue for this q-tile
    float il = 1.0f / l_i;
#pragma unroll
    for (int dt = 0; dt < 8; ++dt) {
      u16x4 o;
#pragma unroll
      for (int r = 0; r < 4; ++r) o[r] = fto16(oacc[dt][r] * il);
      *(u16x4*)&yb[(size_t)(bz * SEQ + qrow) * DMODEL + h * HD + dt * 16 + quad * 4] = o;
    }
  }
}

extern "C" void kernel_launch(void* const* d_in, const int* in_sizes, int n_in,
                              void* d_out, int out_size, void* d_ws, size_t ws_size,
                              hipStream_t stream) {
  (void)in_sizes; (void)n_in; (void)out_size; (void)ws_size;
  const float* x  = (const float*)d_in[0];
  const float* Wq = (const float*)d_in[1];
  const float* Wk = (const float*)d_in[2];
  const float* Wv = (const float*)d_in[3];
  const float* Wp = (const float*)d_in[4];
  const float* qg = (const float*)d_in[5];
  float* out = (float*)d_out;
  char* ws = (char*)d_ws;

  // workspace layout; yb aliases xb (x consumed by GEMM1 before attn writes y)
  unsigned short* xb   = (unsigned short*)(ws + 0);          // 16.78 MB
  unsigned short* Wcat = (unsigned short*)(ws + 16777216);   // 12.58 MB (Wq|Wk|Wv rows)
  unsigned short* Wpq  = (unsigned short*)(ws + 29360128);   // 8.39 MB
  unsigned short* qkvb = (unsigned short*)(ws + 37748736);   // 25.17 MB (bf16 qkv)
  unsigned short* qbuf = (unsigned short*)(ws + 62914560);   // 16.78 MB
  unsigned short* kbuf = (unsigned short*)(ws + 79691776);   // 4.19 MB
  unsigned short* vtb  = (unsigned short*)(ws + 83886080);   // 4.19 MB (V^T)
  unsigned short* yb   = xb;

  prep_kernel<<<28672, 256, 0, stream>>>(Wq, Wk, Wv, Wp, x, Wcat, Wpq, xb);
  gemm_bt<unsigned short><<<dim3(32, 24), 256, 0, stream>>>(xb, Wcat, qkvb, MROWS, NTOT, DMODEL);
  postq_kernel<<<MROWS + 512, 256, 0, stream>>>(qkvb, qg, qbuf, kbuf, vtb);
  attn_kernel<<<dim3(16, NH, 2), 256, 0, stream>>>(qbuf, kbuf, vtb, yb);
  gemm_bt<float><<<dim3(32, 16), 256, 0, stream>>>(yb, Wpq, out, MROWS, DMODEL, DMODEL);
}